// Round 1
// baseline (2838.480 us; speedup 1.0000x reference)
//
#include <hip/hip_runtime.h>

#define N_NODES 50000
#define N_EDGES 1600000
#define IN_DIM 256
#define OUT_DIM 128
#define NEG_SLOPE 0.01f

// ---------------------------------------------------------------------------
// Kernel 1: h = x @ W   (fp32, LDS-tiled; no fp32 MFMA on CDNA4)
// Tile: 64 rows x 128 cols, K-chunk 32. Block = 256 threads,
// each thread computes 4 rows x 8 cols = 32 accumulators.
// ---------------------------------------------------------------------------
#define TM 64
#define TK 32

__global__ __launch_bounds__(256) void gemm_xw(const float* __restrict__ x,
                                               const float* __restrict__ w,
                                               float* __restrict__ h) {
    __shared__ float xs[TK][TM + 1];        // +1 pad: break bank conflicts
    __shared__ float ws[TK][OUT_DIM + 4];   // +4 pad keeps float4 alignment

    const int tid  = threadIdx.x;
    const int row0 = blockIdx.x * TM;
    const int tx = tid & 15;   // 16 col-groups of 8 cols
    const int ty = tid >> 4;   // 16 row-groups of 4 rows

    float acc[4][8];
#pragma unroll
    for (int i = 0; i < 4; ++i)
#pragma unroll
        for (int j = 0; j < 8; ++j) acc[i][j] = 0.0f;

    // x-tile loader mapping: 64 rows x 32 k = 2048 floats / 256 thr = 8 each
    const int loadRow = tid >> 2;        // 0..63
    const int loadK   = (tid & 3) * 8;   // 0,8,16,24
    // w-tile loader mapping: 32 k x 128 cols = 4096 floats / 256 thr = 16 each
    const int wkr  = tid >> 5;           // 0..7
    const int wcol = (tid & 31) * 4;     // 0..124

    for (int kc = 0; kc < IN_DIM; kc += TK) {
        // ---- stage x tile (transposed: xs[k][row]) ----
        float4 xv0, xv1;
        const int gr = row0 + loadRow;
        if (gr < N_NODES) {
            const float4* xp = (const float4*)(x + (size_t)gr * IN_DIM + kc + loadK);
            xv0 = xp[0];
            xv1 = xp[1];
        } else {
            xv0 = make_float4(0.f, 0.f, 0.f, 0.f);
            xv1 = xv0;
        }
        xs[loadK + 0][loadRow] = xv0.x;
        xs[loadK + 1][loadRow] = xv0.y;
        xs[loadK + 2][loadRow] = xv0.z;
        xs[loadK + 3][loadRow] = xv0.w;
        xs[loadK + 4][loadRow] = xv1.x;
        xs[loadK + 5][loadRow] = xv1.y;
        xs[loadK + 6][loadRow] = xv1.z;
        xs[loadK + 7][loadRow] = xv1.w;

        // ---- stage w tile (row-major: ws[k][col]) ----
#pragma unroll
        for (int r = 0; r < 4; ++r) {
            const float4* wp = (const float4*)(w + (size_t)(kc + wkr + r * 8) * OUT_DIM + wcol);
            *(float4*)&ws[wkr + r * 8][wcol] = *wp;
        }
        __syncthreads();

#pragma unroll
        for (int k = 0; k < TK; ++k) {
            float xr[4];
            float wr[8];
#pragma unroll
            for (int i = 0; i < 4; ++i) xr[i] = xs[k][ty * 4 + i];
#pragma unroll
            for (int j = 0; j < 8; ++j) wr[j] = ws[k][tx * 8 + j];
#pragma unroll
            for (int i = 0; i < 4; ++i)
#pragma unroll
                for (int j = 0; j < 8; ++j) acc[i][j] += xr[i] * wr[j];
        }
        __syncthreads();
    }

    // ---- write h tile ----
#pragma unroll
    for (int i = 0; i < 4; ++i) {
        const int gr = row0 + ty * 4 + i;
        if (gr < N_NODES) {
            float* hp = h + (size_t)gr * OUT_DIM + tx * 8;
            float4 v0 = make_float4(acc[i][0], acc[i][1], acc[i][2], acc[i][3]);
            float4 v1 = make_float4(acc[i][4], acc[i][5], acc[i][6], acc[i][7]);
            ((float4*)hp)[0] = v0;
            ((float4*)hp)[1] = v1;
        }
    }
}

// ---------------------------------------------------------------------------
// Kernel 2: edge-parallel SpMM scatter with hw fp32 atomics.
// 32 lanes per edge; each lane: float4 gather from h[col], 4 atomicAdds to
// out[row]. unsafeAtomicAdd -> global_atomic_add_f32 (no CAS loop).
// ---------------------------------------------------------------------------
__global__ __launch_bounds__(256) void spmm_scatter(const float* __restrict__ h,
                                                    const float* __restrict__ vals,
                                                    const int* __restrict__ rows,
                                                    const int* __restrict__ cols,
                                                    float* __restrict__ out) {
    const int gid  = blockIdx.x * 256 + threadIdx.x;
    const int edge = gid >> 5;          // 32 lanes per edge
    if (edge >= N_EDGES) return;
    const int lane = gid & 31;

    const int   r = rows[edge];
    const int   c = cols[edge];
    const float v = vals[edge];

    const float4 m = ((const float4*)(h + (size_t)c * OUT_DIM))[lane];
    float* o = out + (size_t)r * OUT_DIM + lane * 4;
    unsafeAtomicAdd(o + 0, v * m.x);
    unsafeAtomicAdd(o + 1, v * m.y);
    unsafeAtomicAdd(o + 2, v * m.z);
    unsafeAtomicAdd(o + 3, v * m.w);
}

// ---------------------------------------------------------------------------
// Kernel 3: in-place leaky ReLU epilogue.
// ---------------------------------------------------------------------------
__global__ __launch_bounds__(256) void lrelu_inplace(float* __restrict__ out, int n4) {
    const int gid = blockIdx.x * 256 + threadIdx.x;
    if (gid >= n4) return;
    float4* p = (float4*)out;
    float4 v = p[gid];
    v.x = v.x >= 0.f ? v.x : NEG_SLOPE * v.x;
    v.y = v.y >= 0.f ? v.y : NEG_SLOPE * v.y;
    v.z = v.z >= 0.f ? v.z : NEG_SLOPE * v.z;
    v.w = v.w >= 0.f ? v.w : NEG_SLOPE * v.w;
    p[gid] = v;
}

extern "C" void kernel_launch(void* const* d_in, const int* in_sizes, int n_in,
                              void* d_out, int out_size, void* d_ws, size_t ws_size,
                              hipStream_t stream) {
    const float* x    = (const float*)d_in[0];
    const float* w    = (const float*)d_in[1];
    const float* vals = (const float*)d_in[2];
    const int*   rows = (const int*)d_in[3];
    const int*   cols = (const int*)d_in[4];
    float* out = (float*)d_out;
    float* h   = (float*)d_ws;   // 50000*128*4 = 25.6 MB scratch

    // out accumulates via atomics -> must start at zero (harness poisons 0xAA)
    hipMemsetAsync(d_out, 0, (size_t)N_NODES * OUT_DIM * sizeof(float), stream);

    const int gemm_blocks = (N_NODES + TM - 1) / TM;          // 782
    gemm_xw<<<gemm_blocks, 256, 0, stream>>>(x, w, h);

    const int spmm_threads = N_EDGES * 32;
    spmm_scatter<<<(spmm_threads + 255) / 256, 256, 0, stream>>>(h, vals, rows, cols, out);

    const int n4 = N_NODES * OUT_DIM / 4;                     // 1.6M float4
    lrelu_inplace<<<(n4 + 255) / 256, 256, 0, stream>>>(out, n4);
}

// Round 2
// 554.048 us; speedup vs baseline: 5.1232x; 5.1232x over previous
//
#include <hip/hip_runtime.h>

#define N_NODES 50000
#define N_EDGES 1600000
#define IN_DIM 256
#define OUT_DIM 128
#define NEG_SLOPE 0.01f

// ---------------------------------------------------------------------------
// Kernel 1: h = x @ W   (fp32, LDS-tiled; no fp32 MFMA on CDNA4)
// ---------------------------------------------------------------------------
#define TM 64
#define TK 32

__global__ __launch_bounds__(256) void gemm_xw(const float* __restrict__ x,
                                               const float* __restrict__ w,
                                               float* __restrict__ h) {
    __shared__ float xs[TK][TM + 1];
    __shared__ float ws[TK][OUT_DIM + 4];

    const int tid  = threadIdx.x;
    const int row0 = blockIdx.x * TM;
    const int tx = tid & 15;
    const int ty = tid >> 4;

    float acc[4][8];
#pragma unroll
    for (int i = 0; i < 4; ++i)
#pragma unroll
        for (int j = 0; j < 8; ++j) acc[i][j] = 0.0f;

    const int loadRow = tid >> 2;
    const int loadK   = (tid & 3) * 8;
    const int wkr  = tid >> 5;
    const int wcol = (tid & 31) * 4;

    for (int kc = 0; kc < IN_DIM; kc += TK) {
        float4 xv0, xv1;
        const int gr = row0 + loadRow;
        if (gr < N_NODES) {
            const float4* xp = (const float4*)(x + (size_t)gr * IN_DIM + kc + loadK);
            xv0 = xp[0];
            xv1 = xp[1];
        } else {
            xv0 = make_float4(0.f, 0.f, 0.f, 0.f);
            xv1 = xv0;
        }
        xs[loadK + 0][loadRow] = xv0.x;
        xs[loadK + 1][loadRow] = xv0.y;
        xs[loadK + 2][loadRow] = xv0.z;
        xs[loadK + 3][loadRow] = xv0.w;
        xs[loadK + 4][loadRow] = xv1.x;
        xs[loadK + 5][loadRow] = xv1.y;
        xs[loadK + 6][loadRow] = xv1.z;
        xs[loadK + 7][loadRow] = xv1.w;

#pragma unroll
        for (int r = 0; r < 4; ++r) {
            const float4* wp = (const float4*)(w + (size_t)(kc + wkr + r * 8) * OUT_DIM + wcol);
            *(float4*)&ws[wkr + r * 8][wcol] = *wp;
        }
        __syncthreads();

#pragma unroll
        for (int k = 0; k < TK; ++k) {
            float xr[4];
            float wr[8];
#pragma unroll
            for (int i = 0; i < 4; ++i) xr[i] = xs[k][ty * 4 + i];
#pragma unroll
            for (int j = 0; j < 8; ++j) wr[j] = ws[k][tx * 8 + j];
#pragma unroll
            for (int i = 0; i < 4; ++i)
#pragma unroll
                for (int j = 0; j < 8; ++j) acc[i][j] += xr[i] * wr[j];
        }
        __syncthreads();
    }

#pragma unroll
    for (int i = 0; i < 4; ++i) {
        const int gr = row0 + ty * 4 + i;
        if (gr < N_NODES) {
            float* hp = h + (size_t)gr * OUT_DIM + tx * 8;
            ((float4*)hp)[0] = make_float4(acc[i][0], acc[i][1], acc[i][2], acc[i][3]);
            ((float4*)hp)[1] = make_float4(acc[i][4], acc[i][5], acc[i][6], acc[i][7]);
        }
    }
}

// ---------------------------------------------------------------------------
// CSR build: histogram -> single-block scan (in-place counts->offsets,
// cursor copy) -> stable-ish bucket reorder of (col,val) pairs.
// ---------------------------------------------------------------------------
__global__ __launch_bounds__(256) void edge_hist(const int* __restrict__ rows,
                                                 int* __restrict__ counts) {
    const int gid = blockIdx.x * 256 + threadIdx.x;
    if (gid >= N_EDGES) return;
    atomicAdd(&counts[rows[gid]], 1);
}

#define SCAN_T 1024
#define SCAN_C ((N_NODES + SCAN_T - 1) / SCAN_T)   // 49

__global__ __launch_bounds__(SCAN_T) void scan_offsets(int* __restrict__ counts, // in: counts, out: offsets (in-place), [N_NODES+1]
                                                       int* __restrict__ cursor) {
    __shared__ int s[SCAN_T];
    const int t = threadIdx.x;
    const int base = t * SCAN_C;

    int lsum = 0;
#pragma unroll 4
    for (int i = 0; i < SCAN_C; ++i) {
        const int idx = base + i;
        if (idx < N_NODES) lsum += counts[idx];
    }
    s[t] = lsum;
    __syncthreads();

    // Hillis-Steele inclusive scan over 1024 partials
    for (int off = 1; off < SCAN_T; off <<= 1) {
        int v = (t >= off) ? s[t - off] : 0;
        __syncthreads();
        s[t] += v;
        __syncthreads();
    }
    const int excl = s[t] - lsum;
    __syncthreads();

    int off = excl;
    for (int i = 0; i < SCAN_C; ++i) {
        const int idx = base + i;
        if (idx < N_NODES) {
            const int c = counts[idx];
            counts[idx] = off;   // offsets[idx]
            cursor[idx] = off;
            off += c;
        }
    }
    if (t == SCAN_T - 1) counts[N_NODES] = off;   // total == N_EDGES
}

__global__ __launch_bounds__(256) void edge_reorder(const int* __restrict__ rows,
                                                    const int* __restrict__ cols,
                                                    const float* __restrict__ vals,
                                                    int* __restrict__ cursor,
                                                    int* __restrict__ scol,
                                                    float* __restrict__ sval) {
    const int gid = blockIdx.x * 256 + threadIdx.x;
    if (gid >= N_EDGES) return;
    const int r = rows[gid];
    const int pos = atomicAdd(&cursor[r], 1);
    scol[pos] = cols[gid];
    sval[pos] = vals[gid];
}

// ---------------------------------------------------------------------------
// Gather SpMM: one wave (64 lanes) per output row; each lane owns 2 of the
// 128 output dims (float2). Edge (col,val) broadcast via shuffles. Fused
// leaky-ReLU. Every output element written exactly once -> no atomics, no
// zero-init of d_out needed.
// ---------------------------------------------------------------------------
__global__ __launch_bounds__(256) void spmm_gather(const float* __restrict__ h,
                                                   const int* __restrict__ offsets,
                                                   const int* __restrict__ scol,
                                                   const float* __restrict__ sval,
                                                   float* __restrict__ out) {
    const int gwave = (blockIdx.x * 256 + threadIdx.x) >> 6;
    if (gwave >= N_NODES) return;
    const int lane = threadIdx.x & 63;
    const int row  = gwave;

    const int beg = offsets[row];
    const int end = offsets[row + 1];

    float2 acc = make_float2(0.f, 0.f);

    for (int e0 = beg; e0 < end; e0 += 64) {
        const int n = min(64, end - e0);
        int   myc = 0;
        float myv = 0.f;
        if (lane < n) {
            myc = scol[e0 + lane];
            myv = sval[e0 + lane];
        }
        for (int j = 0; j < n; ++j) {
            const int   c = __shfl(myc, j);
            const float v = __shfl(myv, j);
            const float2 m = ((const float2*)(h + (size_t)c * OUT_DIM))[lane];
            acc.x += v * m.x;
            acc.y += v * m.y;
        }
    }

    acc.x = acc.x >= 0.f ? acc.x : NEG_SLOPE * acc.x;
    acc.y = acc.y >= 0.f ? acc.y : NEG_SLOPE * acc.y;
    ((float2*)(out + (size_t)row * OUT_DIM))[lane] = acc;
}

// ---------------------------------------------------------------------------
// Launch
// ---------------------------------------------------------------------------
extern "C" void kernel_launch(void* const* d_in, const int* in_sizes, int n_in,
                              void* d_out, int out_size, void* d_ws, size_t ws_size,
                              hipStream_t stream) {
    const float* x    = (const float*)d_in[0];
    const float* w    = (const float*)d_in[1];
    const float* vals = (const float*)d_in[2];
    const int*   rows = (const int*)d_in[3];
    const int*   cols = (const int*)d_in[4];
    float* out = (float*)d_out;

    // workspace layout (256 B aligned regions)
    char* ws = (char*)d_ws;
    size_t off = 0;
    auto alloc = [&](size_t bytes) {
        void* p = ws + off;
        off = (off + bytes + 255) & ~(size_t)255;
        return p;
    };
    float* h      = (float*)alloc((size_t)N_NODES * OUT_DIM * sizeof(float)); // 25.6 MB
    int*   counts = (int*)  alloc((size_t)(N_NODES + 1) * sizeof(int));       // offsets after scan
    int*   cursor = (int*)  alloc((size_t)N_NODES * sizeof(int));
    int*   scol   = (int*)  alloc((size_t)N_EDGES * sizeof(int));             // 6.4 MB
    float* sval   = (float*)alloc((size_t)N_EDGES * sizeof(float));           // 6.4 MB

    // counts must start at zero (ws is poisoned 0xAA before every call)
    hipMemsetAsync(counts, 0, (size_t)(N_NODES + 1) * sizeof(int), stream);

    const int gemm_blocks = (N_NODES + TM - 1) / TM;
    gemm_xw<<<gemm_blocks, 256, 0, stream>>>(x, w, h);

    const int eblocks = (N_EDGES + 255) / 256;
    edge_hist<<<eblocks, 256, 0, stream>>>(rows, counts);
    scan_offsets<<<1, SCAN_T, 0, stream>>>(counts, cursor);
    edge_reorder<<<eblocks, 256, 0, stream>>>(rows, cols, vals, cursor, scol, sval);

    const int gblocks = (N_NODES * 64 + 255) / 256;   // one wave per row
    spmm_gather<<<gblocks, 256, 0, stream>>>(h, counts, scol, sval, out);
}